// Round 8
// baseline (93.767 us; speedup 1.0000x reference)
//
#include <hip/hip_runtime.h>
#include <hip/hip_fp16.h>

// Joint bilateral filter block — persistent 3-tile blocks with cross-tile
// register prefetch (async-stage split).
// x (1,1,20,96,96) f32; guide_im (N,343) f32, N = 16*96*96 = 147456;
// out n = dd*9216 + h*96 + w uses x depths dd+1..dd+3, H/W zero-pad.
//
// launch_bounds 2nd arg empirically = min BLOCKS/CU on this toolchain:
// cap = 2048/(arg*waves_per_block): (512,6)->40, (512,4)->64, (512,2)->128.
// (256,3) -> cap 170. Conv live ~95 + rbuf 48 = ~155, spill-free.
// LDS = 44288 (tile) + 6912 (partials) = 51200 = 100 granules -> 3 blocks/CU.

#define NPATCH 147456
#define TPB     256        // 4 waves
#define PPB      64        // patches per tile (one per lane)
#define TILES     3        // tiles per persistent block
#define NBLK    768        // 768 * 3 * 64 = 147456; 768/256 CU = 3 blocks/CU
#define PATCH_H 346        // halves per patch: 343 data + 3 pad
#define PATCH_D 173        // dwords per patch (odd -> conflict-free lane reads)
#define NF4    5488        // float4s per 64-patch tile
#define RBUF     12        // prefetched float4 rounds per thread (48 VGPR)

// ---------------- Kernel A: domain branch (runs once, 1 block) --------------
__global__ __launch_bounds__(128) void domain_branch_kernel(
    const float* __restrict__ dn,
    const float* __restrict__ w1, const float* __restrict__ b1,
    const float* __restrict__ w2, const float* __restrict__ b2,
    float* __restrict__ dom_out)
{
    __shared__ float s_in[344];
    __shared__ float s_c1[128];
    const int t = threadIdx.x;
    for (int idx = t; idx < 343; idx += 128) s_in[idx] = dn[idx];
    __syncthreads();
    if (t < 125) {
        const int i = t / 25, j = (t / 5) % 5, k = t % 5;
        float acc = b1[0];
        const float* base = &s_in[i * 49 + j * 7 + k];
#pragma unroll
        for (int dz = 0; dz < 3; ++dz)
#pragma unroll
            for (int dy = 0; dy < 3; ++dy)
#pragma unroll
                for (int dx = 0; dx < 3; ++dx)
                    acc = fmaf(base[dz * 49 + dy * 7 + dx], w1[dz * 9 + dy * 3 + dx], acc);
        s_c1[t] = fmaxf(acc, 0.f);
    }
    __syncthreads();
    if (t < 27) {
        const int dz = t / 9, dy = (t / 3) % 3, dx = t % 3;
        float acc = b2[0];
#pragma unroll
        for (int u = 0; u < 3; ++u)
#pragma unroll
            for (int v = 0; v < 3; ++v)
#pragma unroll
                for (int q = 0; q < 3; ++q)
                    acc = fmaf(s_c1[(dz + u) * 25 + (dy + v) * 5 + (dx + q)],
                               w2[u * 9 + v * 3 + q], acc);
        dom_out[t] = fmaxf(acc, 0.f);
    }
}

// ---------------- helpers ----------------
__device__ __forceinline__ float h2f_lo(unsigned int q) {
    return __half2float(__ushort_as_half((unsigned short)(q & 0xffffu)));
}
__device__ __forceinline__ float h2f_hi(unsigned int q) {
    return __half2float(__ushort_as_half((unsigned short)(q >> 16)));
}
__device__ __forceinline__ float h2f(unsigned short u) {
    return __half2float(__ushort_as_half(u));
}
__device__ __forceinline__ unsigned short f2h(float f) {
    return __half_as_ushort(__float2half(f));
}

// Load row y of absolute z-slice zi of the 7x7x7 fp16 patch (stride-346
// layout) into d[0..6]. zi, y fold to compile-time constants after unrolling.
__device__ __forceinline__ void load_row(const unsigned int* __restrict__ P, float* d,
                                         int zi, int y) {
    const int h0  = zi * 49 + y * 7;       // half offset within patch
    const int par = h0 & 1;                // compile-time
    const int d0  = (h0 - par) >> 1;
    unsigned int q0 = P[d0], q1 = P[d0 + 1], q2 = P[d0 + 2], q3 = P[d0 + 3];
    if (par == 0) {
        d[0] = h2f_lo(q0); d[1] = h2f_hi(q0); d[2] = h2f_lo(q1); d[3] = h2f_hi(q1);
        d[4] = h2f_lo(q2); d[5] = h2f_hi(q2); d[6] = h2f_lo(q3);
    } else {
        d[0] = h2f_hi(q0); d[1] = h2f_lo(q1); d[2] = h2f_hi(q1); d[3] = h2f_lo(q2);
        d[4] = h2f_hi(q2); d[5] = h2f_lo(q3); d[6] = h2f_hi(q3);
    }
}

// Run conv1+fused-conv2 row-tasks (i,j) from (IB,JB) to (IE,JE) inclusive,
// accumulating into a2 (partial).
template<int IB, int JB, int IE, int JE>
__device__ __forceinline__ void run_tasks(const unsigned int* __restrict__ P,
                                          const float* __restrict__ w1, float bb1,
                                          const float* __restrict__ w2,
                                          float (&a2)[3][3][3])
{
#pragma unroll
    for (int i = IB; i <= IE; ++i) {              // c1 z-slab (input slices i..i+2)
        float rw[3][3][7];                        // [u][y%3][k]
        const int j0 = (i == IB) ? JB : 0;
        const int j1 = (i == IE) ? JE : 4;
#pragma unroll
        for (int j = j0; j <= j1; ++j) {
            if (j == j0) {
#pragma unroll
                for (int u = 0; u < 3; ++u)
#pragma unroll
                    for (int dy = 0; dy < 3; ++dy)
                        load_row(P, rw[u][(j + dy) % 3], i + u, j + dy);
            } else {
#pragma unroll
                for (int u = 0; u < 3; ++u)
                    load_row(P, rw[u][(j + 2) % 3], i + u, j + 2);
            }

            float c1r[5];
#pragma unroll
            for (int k = 0; k < 5; ++k) {
                float a = bb1;
#pragma unroll
                for (int u = 0; u < 3; ++u)
#pragma unroll
                    for (int v = 0; v < 3; ++v) {
                        const float* rr = rw[u][(j + v) % 3];
#pragma unroll
                        for (int w = 0; w < 3; ++w)
                            a = fmaf(rr[k + w], w1[u * 9 + v * 3 + w], a);
                    }
                c1r[k] = fmaxf(a, 0.f);
            }

#pragma unroll
            for (int dz2 = 0; dz2 < 3; ++dz2) {
                const int u2 = i - dz2;
                if (u2 >= 0 && u2 < 3) {
#pragma unroll
                    for (int v2 = 0; v2 < 3; ++v2) {
                        const int dy2 = j - v2;
                        if (dy2 >= 0 && dy2 < 3) {
#pragma unroll
                            for (int dx2 = 0; dx2 < 3; ++dx2)
#pragma unroll
                                for (int q = 0; q < 3; ++q)
                                    a2[dz2][dy2][dx2] =
                                        fmaf(c1r[dx2 + q],
                                             w2[u2 * 9 + v2 * 3 + q],
                                             a2[dz2][dy2][dx2]);
                        }
                    }
                }
            }
        }
    }
}

// ---------------- Kernel B: persistent range branch + combine ---------------
__global__ __launch_bounds__(TPB, 3) void jbf_main_kernel(
    const float* __restrict__ guide, const float* __restrict__ x,
    const float* __restrict__ w1, const float* __restrict__ b1,
    const float* __restrict__ w2, const float* __restrict__ b2,
    const float* __restrict__ dom, float* __restrict__ out)
{
    __shared__ unsigned short tile[PPB * PATCH_H];   // 44,288 B
    __shared__ unsigned short part[PPB][54];         //  6,912 B  (total 51,200)

    const int tid  = threadIdx.x;
    const int wid  = tid >> 6;      // wave 0..3
    const int lane = tid & 63;      // patch owned by this thread
    const int g0   = blockIdx.x * TILES;

// write 4 consecutive f32->fp16 elements of tile data at flat position
#define STORE4(IT, C) do {                                       \
        int flat = (IT) * (TPB * 4) + tid * 4;                   \
        int p    = flat / 343;                                   \
        int rs   = flat - p * 343;                               \
        int dst  = p * PATCH_H + rs;                             \
        float v4[4] = {(C).x, (C).y, (C).z, (C).w};              \
        _Pragma("unroll")                                        \
        for (int e = 0; e < 4; ++e) {                            \
            tile[dst] = f2h(v4[e]);                              \
            ++dst; if (++rs == 343) { rs = 0; dst += 3; }        \
        }                                                        \
    } while (0)

    // =================== prologue: stage tile g0 conventionally =============
    {
        const float4* __restrict__ src =
            reinterpret_cast<const float4*>(guide + (size_t)g0 * (PPB * 343));
        float4 buf[4];
#pragma unroll
        for (int k = 0; k < 4; ++k) buf[k] = src[k * TPB + tid];
#pragma unroll 1
        for (int it0 = 0; it0 < 20; it0 += 4) {
#pragma unroll
            for (int k = 0; k < 4; ++k) {
                float4 cur = buf[k];
                int idx = (it0 + 4 + k) * TPB + tid;
                if (idx > NF4 - 1) idx = NF4 - 1;
                buf[k] = src[idx];
                STORE4(it0 + k, cur);
            }
        }
        STORE4(20, buf[0]);
        if (tid < 112) STORE4(21, buf[1]);
    }
    __syncthreads();

    const float bb1 = b1[0];
    const float bb2 = b2[0];

    // =================== persistent tile loop ===============================
#pragma unroll 1
    for (int t = 0; t < TILES; ++t) {
        const bool have_next = (t + 1 < TILES);
        const float4* __restrict__ sn =
            reinterpret_cast<const float4*>(guide +
                (size_t)(g0 + t + 1) * (PPB * 343));

        // ---- issue next tile's first RBUF rounds into registers NOW; they
        // stay in flight across the whole conv phase (async-stage split) ----
        float4 rbuf[RBUF];
        if (have_next) {
#pragma unroll
            for (int r = 0; r < RBUF; ++r) rbuf[r] = sn[r * TPB + tid];
        }

        // ---- conv1+conv2, slab-aligned 4-way split {10,5,5,5} ----
        const unsigned int* __restrict__ P =
            reinterpret_cast<const unsigned int*>(tile) + lane * PATCH_D;

        float a2[3][3][3];
        {
            const float init = (wid == 0) ? bb2 : 0.f;
#pragma unroll
            for (int a = 0; a < 3; ++a)
#pragma unroll
                for (int b = 0; b < 3; ++b)
#pragma unroll
                    for (int c = 0; c < 3; ++c) a2[a][b][c] = init;
        }

        if      (wid == 0) run_tasks<0, 0, 1, 4>(P, w1, bb1, w2, a2); // i=0,1
        else if (wid == 1) run_tasks<2, 0, 2, 4>(P, w1, bb1, w2, a2); // i=2
        else if (wid == 2) run_tasks<3, 0, 3, 4>(P, w1, bb1, w2, a2); // i=3
        else               run_tasks<4, 0, 4, 4>(P, w1, bb1, w2, a2); // i=4

        // sparse fp16 partials: wave1 dz2 0..2 (27), wave2 dz2 1..2 (18),
        // wave3 dz2 2 (9)
        if (wid == 1) {
#pragma unroll
            for (int q = 0; q < 27; ++q)
                part[lane][q] = f2h(a2[q / 9][(q / 3) % 3][q % 3]);
        } else if (wid == 2) {
#pragma unroll
            for (int dz = 1; dz < 3; ++dz)
#pragma unroll
                for (int dy = 0; dy < 3; ++dy)
#pragma unroll
                    for (int dx = 0; dx < 3; ++dx)
                        part[lane][27 + (dz - 1) * 9 + dy * 3 + dx] =
                            f2h(a2[dz][dy][dx]);
        } else if (wid == 3) {
#pragma unroll
            for (int dy = 0; dy < 3; ++dy)
#pragma unroll
                for (int dx = 0; dx < 3; ++dx)
                    part[lane][45 + dy * 3 + dx] = f2h(a2[2][dy][dx]);
        }
        __syncthreads();   // conv reads of tile done; partials visible

        // ---- combine + output (wave 0) ----
        if (wid == 0) {
            const int n   = (g0 + t) * PPB + lane;
            const int dd  = n / 9216;
            const int rem = n - dd * 9216;
            const int h   = rem / 96;
            const int w_  = rem - h * 96;

            float num = 0.f, den = 0.f;
#pragma unroll
            for (int dz = 0; dz < 3; ++dz)
#pragma unroll
                for (int dy = 0; dy < 3; ++dy)
#pragma unroll
                    for (int dx = 0; dx < 3; ++dx) {
                        const int q27 = dz * 9 + dy * 3 + dx;
                        float r2 = a2[dz][dy][dx] + h2f(part[lane][q27]);
                        if (dz >= 1)
                            r2 += h2f(part[lane][27 + (dz - 1) * 9 + dy * 3 + dx]);
                        if (dz == 2)
                            r2 += h2f(part[lane][45 + dy * 3 + dx]);
                        r2 = fmaxf(r2, 0.f);
                        const float wt = fmaf(dom[q27], r2, 1e-10f);
                        const int yy = h - 1 + dy, xx = w_ - 1 + dx;
                        float xv = 0.f;
                        if (yy >= 0 && yy < 96 && xx >= 0 && xx < 96)
                            xv = x[(dd + 1 + dz) * 9216 + yy * 96 + xx];
                        num = fmaf(wt, xv, num);
                        den += wt;
                    }
            out[n] = num / den;
        }

        // ---- write next tile: prefetched rounds, then remainder ----
        if (have_next) {
#pragma unroll
            for (int r = 0; r < RBUF; ++r) STORE4(r, rbuf[r]);

            float4 buf2[4];
#pragma unroll
            for (int k = 0; k < 4; ++k) buf2[k] = sn[(RBUF + k) * TPB + tid];
#pragma unroll 1
            for (int it0 = RBUF; it0 + 4 <= 20; it0 += 4) {   // 12, 16
#pragma unroll
                for (int k = 0; k < 4; ++k) {
                    float4 cur = buf2[k];
                    int idx = (it0 + 4 + k) * TPB + tid;
                    if (idx > NF4 - 1) idx = NF4 - 1;
                    buf2[k] = sn[idx];
                    STORE4(it0 + k, cur);
                }
            }
            STORE4(20, buf2[0]);
            if (tid < 112) STORE4(21, buf2[1]);
            __syncthreads();   // tile t+1 ready
        }
    }
#undef STORE4
}

extern "C" void kernel_launch(void* const* d_in, const int* in_sizes, int n_in,
                              void* d_out, int out_size, void* d_ws, size_t ws_size,
                              hipStream_t stream) {
    const float* x     = (const float*)d_in[0];
    const float* dn    = (const float*)d_in[1];
    const float* guide = (const float*)d_in[2];
    const float* w1_d  = (const float*)d_in[3];
    const float* b1_d  = (const float*)d_in[4];
    const float* w2_d  = (const float*)d_in[5];
    const float* b2_d  = (const float*)d_in[6];
    const float* w1_r  = (const float*)d_in[7];
    const float* b1_r  = (const float*)d_in[8];
    const float* w2_r  = (const float*)d_in[9];
    const float* b2_r  = (const float*)d_in[10];
    float* out = (float*)d_out;
    float* dom = (float*)d_ws;   // 27 floats of scratch

    domain_branch_kernel<<<1, 128, 0, stream>>>(dn, w1_d, b1_d, w2_d, b2_d, dom);
    jbf_main_kernel<<<NBLK, TPB, 0, stream>>>(guide, x, w1_r, b1_r, w2_r,
                                              b2_r, dom, out);
}

// Round 9
// 51.355 us; speedup vs baseline: 1.8259x; 1.8259x over previous
//
#include <hip/hip_runtime.h>
#include <hip/hip_fp16.h>

// Joint bilateral filter block — 4-wave cooperative, thread-per-patch,
// row-aligned fp16 LDS tile (one ds_read_b128 per 7-tap row).
// x (1,1,20,96,96) f32; guide_im (N,343) f32, N = 16*96*96 = 147456;
// out n = dd*9216 + h*96 + w uses x depths dd+1..dd+3, H/W zero-pad.
//
// History: r4 (this structure, 4xb32 rows) = 52.5us. r5-r8 (8-wave /
// persistent / reg-prefetch) all regressed via VGPR spill or lockstep.
// This round: r4 + 16B-aligned rows -> 1 b128/row instead of 4 b32.

#define NPATCH 147456
#define TPB     256        // 4 waves
#define PPB      64        // patches per block (one per lane, all waves share)
#define NBLK   (NPATCH / PPB)   // 2304
#define ROW_H     8        // halves per row: 7 data + 1 pad (16 B aligned)
#define PATCH_H 392        // 49 rows * 8 halves = 784 B per patch
#define PATCH_D 196        // dwords per patch
#define NF4    5488        // float4s per 64-patch tile (64*343/4)

// ---------------- Kernel A: domain branch (runs once, 1 block) --------------
__global__ __launch_bounds__(128) void domain_branch_kernel(
    const float* __restrict__ dn,
    const float* __restrict__ w1, const float* __restrict__ b1,
    const float* __restrict__ w2, const float* __restrict__ b2,
    float* __restrict__ dom_out)
{
    __shared__ float s_in[344];
    __shared__ float s_c1[128];
    const int t = threadIdx.x;
    for (int idx = t; idx < 343; idx += 128) s_in[idx] = dn[idx];
    __syncthreads();
    if (t < 125) {
        const int i = t / 25, j = (t / 5) % 5, k = t % 5;
        float acc = b1[0];
        const float* base = &s_in[i * 49 + j * 7 + k];
#pragma unroll
        for (int dz = 0; dz < 3; ++dz)
#pragma unroll
            for (int dy = 0; dy < 3; ++dy)
#pragma unroll
                for (int dx = 0; dx < 3; ++dx)
                    acc = fmaf(base[dz * 49 + dy * 7 + dx], w1[dz * 9 + dy * 3 + dx], acc);
        s_c1[t] = fmaxf(acc, 0.f);
    }
    __syncthreads();
    if (t < 27) {
        const int dz = t / 9, dy = (t / 3) % 3, dx = t % 3;
        float acc = b2[0];
#pragma unroll
        for (int u = 0; u < 3; ++u)
#pragma unroll
            for (int v = 0; v < 3; ++v)
#pragma unroll
                for (int q = 0; q < 3; ++q)
                    acc = fmaf(s_c1[(dz + u) * 25 + (dy + v) * 5 + (dx + q)],
                               w2[u * 9 + v * 3 + q], acc);
        dom_out[t] = fmaxf(acc, 0.f);
    }
}

// ---------------- helpers ----------------
__device__ __forceinline__ float h2f_lo(unsigned int q) {
    return __half2float(__ushort_as_half((unsigned short)(q & 0xffffu)));
}
__device__ __forceinline__ float h2f_hi(unsigned int q) {
    return __half2float(__ushort_as_half((unsigned short)(q >> 16)));
}
__device__ __forceinline__ unsigned short f2h(float f) {
    return __half_as_ushort(__float2half(f));
}

// Load row y of absolute z-slice zi (16B-aligned, 8-half rows) into d[0..6].
// One ds_read_b128. zi, y fold to compile-time constants after unrolling.
__device__ __forceinline__ void load_row(const unsigned int* __restrict__ P, float* d,
                                         int zi, int y) {
    const int d0 = zi * 28 + y * 4;        // dword offset, multiple of 4 -> 16B
    const uint4 q = *reinterpret_cast<const uint4*>(P + d0);
    d[0] = h2f_lo(q.x); d[1] = h2f_hi(q.x);
    d[2] = h2f_lo(q.y); d[3] = h2f_hi(q.y);
    d[4] = h2f_lo(q.z); d[5] = h2f_hi(q.z);
    d[6] = h2f_lo(q.w);
}

// Run conv1+fused-conv2 row-tasks (i,j) from (IB,JB) to (IE,JE) inclusive,
// in row-major task order, accumulating into a2 (partial).
template<int IB, int JB, int IE, int JE>
__device__ __forceinline__ void run_tasks(const unsigned int* __restrict__ P,
                                          const float* __restrict__ w1, float bb1,
                                          const float* __restrict__ w2,
                                          float (&a2)[3][3][3])
{
#pragma unroll
    for (int i = IB; i <= IE; ++i) {              // c1 z-slab (input slices i..i+2)
        float rw[3][3][7];                        // [u][y%3][k]
        const int j0 = (i == IB) ? JB : 0;
        const int j1 = (i == IE) ? JE : 4;
#pragma unroll
        for (int j = j0; j <= j1; ++j) {
            if (j == j0) {
#pragma unroll
                for (int u = 0; u < 3; ++u)
#pragma unroll
                    for (int dy = 0; dy < 3; ++dy)
                        load_row(P, rw[u][(j + dy) % 3], i + u, j + dy);
            } else {
#pragma unroll
                for (int u = 0; u < 3; ++u)
                    load_row(P, rw[u][(j + 2) % 3], i + u, j + 2);
            }

            // c1 row (i, j, k=0..4)
            float c1r[5];
#pragma unroll
            for (int k = 0; k < 5; ++k) {
                float a = bb1;
#pragma unroll
                for (int u = 0; u < 3; ++u)
#pragma unroll
                    for (int v = 0; v < 3; ++v) {
                        const float* rr = rw[u][(j + v) % 3];
#pragma unroll
                        for (int w = 0; w < 3; ++w)
                            a = fmaf(rr[k + w], w1[u * 9 + v * 3 + w], a);
                    }
                c1r[k] = fmaxf(a, 0.f);
            }

            // fused conv2 accumulation
#pragma unroll
            for (int dz2 = 0; dz2 < 3; ++dz2) {
                const int u2 = i - dz2;
                if (u2 >= 0 && u2 < 3) {
#pragma unroll
                    for (int v2 = 0; v2 < 3; ++v2) {
                        const int dy2 = j - v2;
                        if (dy2 >= 0 && dy2 < 3) {
#pragma unroll
                            for (int dx2 = 0; dx2 < 3; ++dx2)
#pragma unroll
                                for (int q = 0; q < 3; ++q)
                                    a2[dz2][dy2][dx2] =
                                        fmaf(c1r[dx2 + q],
                                             w2[u2 * 9 + v2 * 3 + q],
                                             a2[dz2][dy2][dx2]);
                        }
                    }
                }
            }
        }
    }
}

// ---------------- Kernel B: range branch + bilateral combine ----------------
__global__ __launch_bounds__(TPB, 3) void jbf_main_kernel(
    const float* __restrict__ guide, const float* __restrict__ x,
    const float* __restrict__ w1, const float* __restrict__ b1,
    const float* __restrict__ w2, const float* __restrict__ b2,
    const float* __restrict__ dom, float* __restrict__ out)
{
    // partials buffer aliases the (dead-by-then) patch tile: 50,176 B total
    union SM {
        unsigned short tile[PPB * PATCH_H];   // 50,176 B
        float part[3][PPB][27];               // 20,736 B
    };
    __shared__ SM sm;

    const int tid  = threadIdx.x;
    const int wid  = tid >> 6;      // wave 0..3
    const int lane = tid & 63;      // patch owned by this thread
    const int blk  = blockIdx.x;

    // ============== stage 64 patches (21952 f32, contiguous) -> fp16 LDS ===
    // element (p, e) -> row r = e/7, x = e%7; dst = p*392 + r*8 + x
    const float4* __restrict__ src =
        reinterpret_cast<const float4*>(guide + (size_t)blk * (PPB * 343));

#define STORE4(IT, C) do {                                       \
        int flat = (IT) * (TPB * 4) + tid * 4;                   \
        int p    = flat / 343;                                   \
        int e    = flat - p * 343;                               \
        int r    = e / 7;                                        \
        int xx_  = e - r * 7;                                    \
        int dst  = p * PATCH_H + r * ROW_H + xx_;                \
        float v4[4] = {(C).x, (C).y, (C).z, (C).w};              \
        _Pragma("unroll")                                        \
        for (int el = 0; el < 4; ++el) {                         \
            sm.tile[dst] = f2h(v4[el]);                          \
            ++dst; if (++xx_ == 7) { xx_ = 0; ++dst; }           \
        }                                                        \
    } while (0)

    {
        float4 buf[4];
#pragma unroll
        for (int k = 0; k < 4; ++k) buf[k] = src[k * TPB + tid];

#pragma unroll 1
        for (int it0 = 0; it0 < 20; it0 += 4) {     // processes iters 0..19
#pragma unroll
            for (int k = 0; k < 4; ++k) {
                float4 cur = buf[k];
                int idx = (it0 + 4 + k) * TPB + tid;
                if (idx > NF4 - 1) idx = NF4 - 1;   // clamp (safe dup load)
                buf[k] = src[idx];
                STORE4(it0 + k, cur);
            }
        }
        STORE4(20, buf[0]);                  // iter 20: 5120+tid < 5488, all valid
        if (tid < 112) STORE4(21, buf[1]);   // iter 21 partial: 5376+tid < 5488
    }
#undef STORE4
    __syncthreads();

    // ===================== per-thread conv1+conv2 (4-way task split) ========
    const unsigned int* __restrict__ P =
        reinterpret_cast<const unsigned int*>(sm.tile) + lane * PATCH_D;
    const float bb1 = b1[0];

    float a2[3][3][3];
    {
        const float init = (wid == 0) ? b2[0] : 0.f;   // bias added exactly once
#pragma unroll
        for (int a = 0; a < 3; ++a)
#pragma unroll
            for (int b = 0; b < 3; ++b)
#pragma unroll
                for (int c = 0; c < 3; ++c) a2[a][b][c] = init;
    }

    if      (wid == 0) run_tasks<0, 0, 1, 1>(P, w1, bb1, w2, a2);  // 7 tasks
    else if (wid == 1) run_tasks<1, 2, 2, 3>(P, w1, bb1, w2, a2);  // 7 tasks
    else if (wid == 2) run_tasks<2, 4, 3, 4>(P, w1, bb1, w2, a2);  // 6 tasks
    else               run_tasks<4, 0, 4, 4>(P, w1, bb1, w2, a2);  // 5 tasks

    __syncthreads();     // all tile reads complete before aliasing as `part`

    if (wid != 0) {
#pragma unroll
        for (int t = 0; t < 27; ++t)
            sm.part[wid - 1][lane][t] = a2[t / 9][(t / 3) % 3][t % 3];
    }
    __syncthreads();

    // ===================== combine + bilateral (wave 0 only) ================
    if (wid == 0) {
        const int n   = blk * PPB + lane;
        const int dd  = n / 9216;
        const int rem = n - dd * 9216;
        const int h   = rem / 96;
        const int w_  = rem - h * 96;

        float num = 0.f, den = 0.f;
#pragma unroll
        for (int dz = 0; dz < 3; ++dz)
#pragma unroll
            for (int dy = 0; dy < 3; ++dy)
#pragma unroll
                for (int dx = 0; dx < 3; ++dx) {
                    const int t = dz * 9 + dy * 3 + dx;
                    const float r2 = fmaxf(a2[dz][dy][dx] + sm.part[0][lane][t]
                                           + sm.part[1][lane][t]
                                           + sm.part[2][lane][t], 0.f);
                    const float wt = fmaf(dom[t], r2, 1e-10f);
                    const int yy = h - 1 + dy, xx = w_ - 1 + dx;
                    float xv = 0.f;
                    if (yy >= 0 && yy < 96 && xx >= 0 && xx < 96)
                        xv = x[(dd + 1 + dz) * 9216 + yy * 96 + xx];
                    num = fmaf(wt, xv, num);
                    den += wt;
                }
        out[n] = num / den;
    }
}

extern "C" void kernel_launch(void* const* d_in, const int* in_sizes, int n_in,
                              void* d_out, int out_size, void* d_ws, size_t ws_size,
                              hipStream_t stream) {
    const float* x     = (const float*)d_in[0];
    const float* dn    = (const float*)d_in[1];
    const float* guide = (const float*)d_in[2];
    const float* w1_d  = (const float*)d_in[3];
    const float* b1_d  = (const float*)d_in[4];
    const float* w2_d  = (const float*)d_in[5];
    const float* b2_d  = (const float*)d_in[6];
    const float* w1_r  = (const float*)d_in[7];
    const float* b1_r  = (const float*)d_in[8];
    const float* w2_r  = (const float*)d_in[9];
    const float* b2_r  = (const float*)d_in[10];
    float* out = (float*)d_out;
    float* dom = (float*)d_ws;   // 27 floats of scratch

    domain_branch_kernel<<<1, 128, 0, stream>>>(dn, w1_d, b1_d, w2_d, b2_d, dom);
    jbf_main_kernel<<<NBLK, TPB, 0, stream>>>(guide, x, w1_r, b1_r, w2_r,
                                              b2_r, dom, out);
}